// Round 7
// baseline (146.810 us; speedup 1.0000x reference)
//
#include <hip/hip_runtime.h>
#include <math.h>

// DILATE / soft-DTW — round 19: TWO-WAVE SPLIT per problem (fill all SIMDs).
// r18 post-mortem: structure is issue/pipe-bound (~373 cyc/step vs ~230-350
// issue floor, trans-dominated); order-pinning neutral. 512 single-wave
// blocks use only 2 of 4 SIMDs (and trans pipes) per CU.
// r19: block = 128 thr = 2 waves; wave0 rows 1-80, wave1 rows 81-160
// (2 rows/lane x 40 lanes; lanes 40-63 junk, self-contained). 1024 waves
// -> every SIMD busy; per-wave per-step work 15 -> 10 trans ops.
// Seam row 80->81: LDS ring indexed by wall-step t. Wave0 lane39 publishes
// its s=1 (row 80) (value,dual) each step — .y then .x (x is the flag);
// wave1 reads slot t (x then y, volatile, in-order DS) at step START,
// sentinel-checks (NaN 0x7FC00000) at step END, injects via the existing
// DPP old-injection. Wave1's schedule is shifted +1 diag (t = i+j-1) ->
// 2 steps of slack; spin exits immediately in steady state; wave0 never
// waits -> no deadlock (co-resident waves of one block).
// Junk-cell analysis as r17: exp args <= 0 always, ~1e12 junk borders get
// weight exactly 0 by underflow; every real cell sees exact real inputs.
// Real-cell op order/dataflow identical to r17/r18 -> absmax 0.0.
// Kept: C2-domain carry (GLN2*C2==1 exact), subtract-form exp args (r5),
// 4-ahead P prefetch, forward-mode AD.

#define NN     160
#define BC_TOT 512
#define B_SZ   64
#define C_SZ   8
#define BIGC2  1e12f              // border sentinel in C2 domain
#define SC2    12.01122405f       // sqrt(C2), C2 = 144.269504089
#define GLN2   0.0069314718056f   // gamma*ln2 == 1/C2
#define SENT_I 0x7FC00000         // NaN bit pattern = "slot empty"
#define RSLOTS 336                // ring slots (0..320 used)

__device__ __forceinline__ float fexp2(float x) {
#if __has_builtin(__builtin_amdgcn_exp2f)
    return __builtin_amdgcn_exp2f(x);
#else
    return exp2f(x);
#endif
}
__device__ __forceinline__ float flog2(float x) {
#if __has_builtin(__builtin_amdgcn_logf)
    return __builtin_amdgcn_logf(x);
#else
    return log2f(x);
#endif
}
__device__ __forceinline__ float frcp(float x) {
#if __has_builtin(__builtin_amdgcn_rcpf)
    return __builtin_amdgcn_rcpf(x);
#else
    return 1.0f / x;
#endif
}
// lane i <- lane i-1; lane 0 <- old (bound_ctrl=false). Standard scan idiom.
__device__ __forceinline__ float dpp_up1_inj(float old, float x) {
    int oi = __builtin_bit_cast(int, old);
    int xi = __builtin_bit_cast(int, x);
    return __builtin_bit_cast(float,
        __builtin_amdgcn_update_dpp(oi, xi, 0x138, 0xF, 0xF, false)); // wave_shr1
}

// One wall-step: 2 cells (sub-rows 0,1). Op order per cell identical to r17.
#define STEP(PV0, T_) do {                                                    \
    float rvx = BIGC2, rvy = 0.0f;                                            \
    const volatile float* rp_ = (const volatile float*)&ring[(T_)];           \
    if (cons) { rvx = rp_[0]; rvy = rp_[1]; }  /* issue early, check late */  \
    const float mn0 = fminf(b0, fminf(a0, r0));                               \
    const float mn1 = fminf(b1, fminf(a1, r1));                               \
    const float ed0 = fexp2(mn0 - b0);   /* SUBTRACT form (r5 rule) */        \
    const float ev0 = fexp2(mn0 - a0);                                        \
    const float eh0 = fexp2(mn0 - r0);                                        \
    const float ed1 = fexp2(mn1 - b1);                                        \
    const float ev1 = fexp2(mn1 - a1);                                        \
    const float eh1 = fexp2(mn1 - r1);                                        \
    const float ss0 = (ed0 + ev0) + eh0;   /* >= 1 */                         \
    const float ss1 = (ed1 + ev1) + eh1;                                      \
    const float rs0 = frcp(ss0);                                              \
    const float rs1 = frcp(ss1);                                              \
    const float dt0 = trS0 - (PV0);                                           \
    const float dt1 = trS1 - pva;                                             \
    const float n0 = __builtin_fmaf(dt0, dt0, mn0) - flog2(ss0);              \
    const float n1 = __builtin_fmaf(dt1, dt1, mn1) - flog2(ss1);              \
    const float nm0 = __builtin_fmaf(ed0, bd0,                                \
                      __builtin_fmaf(ev0, ad0, eh0 * g0));                    \
    const float nm1 = __builtin_fmaf(ed1, bd1,                                \
                      __builtin_fmaf(ev1, ad1, eh1 * g1));                    \
    const float dj1 = dj0 - 2.0f;                                             \
    const float nd0 = __builtin_fmaf(nm0, rs0, dj0 * dj0);                    \
    const float nd1 = __builtin_fmaf(nm1, rs1, dj1 * dj1);                    \
    if (pub) {   /* row-80 publish: .y first, .x (flag) second */             \
        volatile float* wp_ = (volatile float*)&ring[(T_) + 1];               \
        wp_[1] = nd1;                                                         \
        wp_[0] = n1;                                                          \
    }                                                                         \
    if (cons) {  /* steady state: exits immediately (2-step slack) */         \
        while (__builtin_amdgcn_readfirstlane(                                \
                   __builtin_bit_cast(int, rvx)) == (int)SENT_I) {            \
            rvx = rp_[0]; rvy = rp_[1];                                       \
        }                                                                     \
    }                                                                         \
    b1 = a1; bd1 = ad1; a1 = n0; ad1 = nd0;                                   \
    b0 = a0; bd0 = ad0;                                                       \
    a0  = dpp_up1_inj(rvx, n1);   /* lane0 <- border / seam value */          \
    ad0 = dpp_up1_inj(rvy, nd1);                                              \
    r0 = n0; r1 = n1; g0 = nd0; g1 = nd1;                                     \
    pva = (PV0); dj0 += 1.0f;                                                 \
} while (0)

__global__ __launch_bounds__(128, 1)
void dtw_fwd_kernel(const float* __restrict__ input,
                    const float* __restrict__ target,
                    float* __restrict__ sdtw,    // BC_TOT: R[N,N]
                    float* __restrict__ wlt)     // BC_TOT: Rdot[N,N]/N^2
{
    const int k    = blockIdx.x;
    const int tid  = threadIdx.x;
    const int wv   = tid >> 6;                   // 0: rows 1-80, 1: rows 81-160
    const int lane = tid & 63;

    __shared__ __align__(16) float  Pp[544];     // Pp[x] = pg[x-192]*SC2, pad 0
    __shared__ __align__(8)  float2 ring[RSLOTS];// seam: (rC2,rdot) @ slot=step

    const float* tg = target + (size_t)k * NN;
    const float* pg = input  + (size_t)k * NN;
    for (int x = tid; x < 544; x += 128) {
        const int v = x - 192;
        Pp[x] = ((unsigned)v < (unsigned)NN) ? pg[v] * SC2 : 0.0f;
    }
    for (int x = tid; x < RSLOTS; x += 128) {
        float2 z;
        z.x = (x == 0) ? BIGC2 : __builtin_bit_cast(float, (int)SENT_I);
        z.y = 0.0f;
        ring[x] = z;
    }
    // lane owns rows rowb+1, rowb+2 (1-based), active when lane < 40
    const int  rowb = 80 * wv + 2 * lane;
    const bool act  = (lane < 40);
    const float trS0 = act ? tg[rowb]     * SC2 : 0.0f;
    const float trS1 = act ? tg[rowb + 1] * SC2 : 0.0f;
    __syncthreads();

    const bool pub  = (wv == 0) && (lane == 39); // publishes row 80 (its s=1)
    const bool cons = (wv == 1);                 // lane0 injects row 80 values

    // rolling state (C2 domain): r/g = left; a/ad = up; b/bd = diag.
    float r0 = BIGC2, r1 = BIGC2, g0 = 0.0f, g1 = 0.0f;
    float a0 = BIGC2, a1 = BIGC2, ad0 = 0.0f, ad1 = 0.0f;
    float b0 = (wv == 0 && lane == 0) ? 0.0f : BIGC2;  // R[0][0] = 0 exact
    float b1 = BIGC2, bd0 = 0.0f, bd1 = 0.0f;
    float pva = 0.0f;                            // P value of step t-1 (s=1)
    // dj = j - i for s=0: wave0 t-4l; wave1 (shifted +1): t-4l-161
    float dj0 = (wv == 0) ? (float)(-4 * lane) : (float)(-4 * lane - 161);
    // P index: idx = pb + t; wave0 pb = 192-2l, wave1 pb = 111-2l (clamped)
    int pb = (wv == 0) ? (192 - 2 * lane) : (111 - 2 * lane);
    if (pb < 0) pb = 0;                          // junk lanes: any pad is fine

    float pf0 = Pp[pb + 0], pf1 = Pp[pb + 1], pf2 = Pp[pb + 2], pf3 = Pp[pb + 3];

    // 79 blocks of 4 steps + 4 epilogue = 320 steps (t = 0..319)
    for (int tb = 0; tb < 79; ++tb) {
        const int t4 = 4 * tb;
        const float q0 = Pp[pb + t4 + 4];
        const float q1 = Pp[pb + t4 + 5];
        const float q2 = Pp[pb + t4 + 6];
        const float q3 = Pp[pb + t4 + 7];
        STEP(pf0, t4 + 0); STEP(pf1, t4 + 1);
        STEP(pf2, t4 + 2); STEP(pf3, t4 + 3);
        pf0 = q0; pf1 = q1; pf2 = q2; pf3 = q3;
    }
    STEP(pf0, 316); STEP(pf1, 317); STEP(pf2, 318); STEP(pf3, 319);

    // (160,160) = wave1 lane39 s=1 at t=319; in r1/g1 after final rotation.
    if (wv == 1 && lane == 39) {
        sdtw[k] = r1 * GLN2;                     // back to normal domain
        wlt[k]  = g1 * (1.0f / (NN * NN));
    }
}

// final reduction: per-batch means + scalar loss. One wave (64 threads = B).
__global__ __launch_bounds__(64)
void finalize_kernel(const float* __restrict__ sdtw,
                     const float* __restrict__ wlt,
                     float* __restrict__ out)
{
    const int b = threadIdx.x;   // 0..63
    float ls = 0.0f, lt = 0.0f;
    #pragma unroll
    for (int c = 0; c < C_SZ; ++c) {
        ls += sdtw[b * C_SZ + c];
        lt += wlt[b * C_SZ + c];
    }
    ls *= (1.0f / C_SZ);
    lt *= (1.0f / C_SZ);
    out[1 + b]        = ls;
    out[1 + B_SZ + b] = lt;
    float v = 0.5f * ls + 0.5f * lt;
    #pragma unroll
    for (int o = 32; o > 0; o >>= 1) v += __shfl_down(v, o);
    if (b == 0) out[0] = v * (1.0f / B_SZ);
}

extern "C" void kernel_launch(void* const* d_in, const int* in_sizes, int n_in,
                              void* d_out, int out_size, void* d_ws, size_t ws_size,
                              hipStream_t stream) {
    const float* input  = (const float*)d_in[0];
    const float* target = (const float*)d_in[1];
    float* out = (float*)d_out;   // 129 floats

    float* sdtw = (float*)d_ws;                 // 512 floats
    float* wlt  = sdtw + BC_TOT;                // 512 floats

    dtw_fwd_kernel<<<BC_TOT, 128, 0, stream>>>(input, target, sdtw, wlt);
    finalize_kernel<<<1, 64, 0, stream>>>(sdtw, wlt, out);
}

// Round 8
// 102.717 us; speedup vs baseline: 1.4293x; 1.4293x over previous
//
#include <hip/hip_runtime.h>
#include <math.h>

// DILATE / soft-DTW — round 20: r12's 3-wave band pipeline with BARRIERS
// REPLACED BY PER-CHUNK FLAG SYNC (free-running waves), KPH 16 -> 8.
// Model (r17/r18 counters): kernel is trans-pipe-bound (~15 trans/step x
// ~16 cyc = 240 of 380 cyc wall; VALUBusy 35% chip = ~70%/active SIMD).
// Fixed total trans work => levers are wave count and utilization. r12's
// 3-wave/problem split (1536 waves, 71% util) was right; its cost was the
// all-wave barrier per phase (42/66 wave-phases active + drain). r19's
// per-STEP handshake was fatal (VGPR 20, 727 cyc/step). r20 syncs per
// CHUNK (8 steps): producer publishes per step, then lgkmcnt(0) + one
// flag store; consumer spins on a broadcast ds_read (uniform branch,
// ~1 iter steady-state: producer is structurally 9 chunks ahead).
// Deadlock-free: producers never wait; final sentinel flag covers the
// consumer's trailing junk chunks. All consumed slots are flag-gated
// writes; junk flows only into junk cells (r12's analysis, verified).
// Per-cell op order is verbatim r12 -> absmax 0.0.
// Kept: C2-domain carry (GLN2*C2==1 exact), subtract-form exp args (r5),
// DPP old-injection, lane63 b64 publish, 512 x 192 launch.

#define NN     160
#define BC_TOT 512
#define B_SZ   64
#define C_SZ   8
#define BIGC2  1e12f              // border sentinel in C2 domain
#define SC2    12.01122405f       // sqrt(C2), C2 = 144.269504089
#define GLN2   0.0069314718056f   // gamma*ln2 == 1/C2
#define KPH    8                  // diag steps per chunk
#define NCH    28                 // chunks per wave (64+160-1 = 223 <= 224)
#define RSZ    360                // float2 ring slots (reads up to 353)

__device__ __forceinline__ float fexp2(float x) {
#if __has_builtin(__builtin_amdgcn_exp2f)
    return __builtin_amdgcn_exp2f(x);
#else
    return exp2f(x);
#endif
}
__device__ __forceinline__ float flog2(float x) {
#if __has_builtin(__builtin_amdgcn_logf)
    return __builtin_amdgcn_logf(x);
#else
    return log2f(x);
#endif
}
__device__ __forceinline__ float frcp(float x) {
#if __has_builtin(__builtin_amdgcn_rcpf)
    return __builtin_amdgcn_rcpf(x);
#else
    return 1.0f / x;
#endif
}
// lane i <- lane i-1; lane 0 <- old (bound_ctrl=false). Standard scan idiom.
__device__ __forceinline__ float dpp_up1_inj(float old, float x) {
    int oi = __builtin_bit_cast(int, old);
    int xi = __builtin_bit_cast(int, x);
    return __builtin_bit_cast(float,
        __builtin_amdgcn_update_dpp(oi, xi, 0x138, 0xF, 0xF, false)); // wave_shr1
}
// LDS-only barrier (no vmcnt drain). 0xC07F = vmcnt(63) expcnt(7) lgkmcnt(0).
__device__ __forceinline__ void barrier_lds() {
    __asm__ __volatile__("" ::: "memory");
    __builtin_amdgcn_s_waitcnt(0xC07F);
    __builtin_amdgcn_s_barrier();
    __asm__ __volatile__("" ::: "memory");
}

__global__ __launch_bounds__(192, 1)
void dtw_fwd_kernel(const float* __restrict__ input,
                    const float* __restrict__ target,
                    float* __restrict__ sdtw,    // BC_TOT: R[N,N]
                    float* __restrict__ wlt)     // BC_TOT: Rdot[N,N]/N^2
{
    const int k    = blockIdx.x;
    const int tid  = threadIdx.x;
    const int w    = tid >> 6;
    const int lane = tid & 63;

    __shared__ __align__(16) float  Pp[4][520];  // replica s: Pp[s][y]=V(y+s)*SC2
    __shared__ __align__(16) float2 bRG[2][RSZ]; // ring: (rC2, rdot) @ slot=diag
    __shared__ int flags[2];                     // chunks completed by wave 0/1

    const float* tg = target + (size_t)k * NN;
    const float* pg = input  + (size_t)k * NN;
    // V(z) = P[z-192]*SC2 for z in [192,352), else 0
    for (int x = tid; x < 520; x += 192) {
        #pragma unroll
        for (int s = 0; s < 4; ++s) {
            const int v = x + s - 192;
            Pp[s][x] = ((unsigned)v < (unsigned)NN) ? pg[v] * SC2 : 0.0f;
        }
    }
    if (tid < 2) flags[tid] = 0;
    const float trS = (tid < NN) ? tg[tid] * SC2 : 0.0f;
    barrier_lds();   // ONLY barrier in the kernel (staging + flag init)

    const bool isL0    = (lane == 0);
    const bool pubw    = (w < 2);
    const bool isL63p  = (lane == 63) && pubw;
    const int  ti2     = 2 * (tid + 1);          // 2*i
    const int  c0      = 8 * w;                  // first chunk of this wave
    const unsigned fPrevA = (unsigned)(unsigned long long)&flags[(w > 0) ? (w - 1) : 0];

    // rolling state (C2 domain): r1 own prev; u1/u2 up-lane prev/prev-prev
    // (lane 0 auto-carries ring values via DPP injection). Dual: s1,v1,v2.
    float r1 = BIGC2, u1 = BIGC2, u2 = BIGC2;
    float s1 = 0.0f,  v1 = 0.0f,  v2 = 0.0f;

    for (int c = c0; c < c0 + NCH; ++c) {
        if (w > 0) {                 // wait: producer finished global chunk c
            int fv;
            for (;;) {
                asm volatile("ds_read_b32 %0, %1\n\ts_waitcnt lgkmcnt(0)"
                             : "=v"(fv) : "v"(fPrevA) : "memory");
                if (__builtin_amdgcn_readfirstlane(fv) >= c + 1) break;
            }
        }
        const int dlo = 2 + c * KPH;
        // ring window slots [dlo-2, dlo+7] (10): 5 aligned b128 broadcast reads
        float rgx[10], rgd[10];
        if (w > 0) {
            const float4* q = (const float4*)&bRG[w - 1][dlo - 2];
            #pragma unroll
            for (int x = 0; x < 5; ++x) {
                const float4 v4 = q[x];
                rgx[2 * x]     = v4.x; rgd[2 * x]     = v4.y;
                rgx[2 * x + 1] = v4.z; rgd[2 * x + 1] = v4.w;
            }
        } else {
            #pragma unroll
            for (int x = 0; x < 10; ++x) { rgx[x] = BIGC2; rgd[x] = 0.0f; }
            if (c == 0) rgx[0] = 0.0f;           // R[0][0] = 0 seed at d=2
        }
        // P window (pre-scaled): pvv(u) = V(A+u), aligned replica reads
        float pvv[KPH];
        {
            const int A  = 192 - tid + KPH * c;
            const int sA = A & 3;
            const float4* pq = (const float4*)&Pp[sA][A - sA];
            #pragma unroll
            for (int x = 0; x < 2; ++x) {
                const float4 p4 = pq[x];
                pvv[4 * x]     = p4.x; pvv[4 * x + 1] = p4.y;
                pvv[4 * x + 2] = p4.z; pvv[4 * x + 3] = p4.w;
            }
        }
        if (c == c0) {       // one-time boundary injection (first chunk)
            u1 = isL0 ? rgx[1] : BIGC2;  u2 = isL0 ? rgx[0] : BIGC2;
            v1 = isL0 ? rgd[1] : 0.0f;   v2 = isL0 ? rgd[0] : 0.0f;
        }
        float djf = (float)(dlo - ti2);          // j - i at u=0
        #pragma unroll
        for (int u = 0; u < KPH; ++u) {
            const int d = dlo + u;
            const float vdC = u2;                // R_c2[i-1][j-1]
            const float vuC = u1;                // R_c2[i-1][j]
            const float vlC = r1;                // R_c2[i][j-1]
            const float gd = v2, gu = v1, gl = s1;
            const float mnC = fminf(vdC, fminf(vuC, vlC));
            // SUBTRACT form mandatory (r5): exact 0 at min, always <= 0.
            const float ed = fexp2(mnC - vdC);
            const float ev = fexp2(mnC - vuC);
            const float eh = fexp2(mnC - vlC);
            const float ss = ed + ev + eh;       // >= 1
            const float rs = frcp(ss);
            const float dtS = trS - pvv[u];
            const float rC2 = __builtin_fmaf(dtS, dtS, mnC) - flog2(ss);
            const float num = __builtin_fmaf(ed, gd,
                              __builtin_fmaf(ev, gu, eh * gl));
            const float rdot = __builtin_fmaf(num, rs, djf * djf);
            if (isL63p) {                        // single b64 publish
                float2 pb; pb.x = rC2; pb.y = rdot;
                bRG[w][d] = pb;
            }
            if (d == 2 * NN) {
                if (tid == NN - 1) {             // cell (160,160)
                    sdtw[k] = rC2 * GLN2;        // back to normal domain
                    wlt[k]  = rdot * (1.0f / (NN * NN));
                }
            }
            u2 = u1;
            u1 = dpp_up1_inj(rgx[u + 2], rC2);   // lane0 <- ring slot d
            v2 = v1;
            v1 = dpp_up1_inj(rgd[u + 2], rdot);
            r1 = rC2;
            s1 = rdot;
            djf += 1.0f;
        }
        if (pubw) {          // publish chunk-complete flag (data-ordered)
            asm volatile("s_waitcnt lgkmcnt(0)" ::: "memory");
            if (lane == 0) *(volatile int*)&flags[w] = c + 1;
        }
    }
    if (pubw) {              // sentinel: consumer's trailing junk chunks
        asm volatile("s_waitcnt lgkmcnt(0)" ::: "memory");
        if (lane == 0) *(volatile int*)&flags[w] = 1 << 20;
    }
}

// final reduction: per-batch means + scalar loss. One wave (64 threads = B).
__global__ __launch_bounds__(64)
void finalize_kernel(const float* __restrict__ sdtw,
                     const float* __restrict__ wlt,
                     float* __restrict__ out)
{
    const int b = threadIdx.x;   // 0..63
    float ls = 0.0f, lt = 0.0f;
    #pragma unroll
    for (int c = 0; c < C_SZ; ++c) {
        ls += sdtw[b * C_SZ + c];
        lt += wlt[b * C_SZ + c];
    }
    ls *= (1.0f / C_SZ);
    lt *= (1.0f / C_SZ);
    out[1 + b]        = ls;
    out[1 + B_SZ + b] = lt;
    float v = 0.5f * ls + 0.5f * lt;
    #pragma unroll
    for (int o = 32; o > 0; o >>= 1) v += __shfl_down(v, o);
    if (b == 0) out[0] = v * (1.0f / B_SZ);
}

extern "C" void kernel_launch(void* const* d_in, const int* in_sizes, int n_in,
                              void* d_out, int out_size, void* d_ws, size_t ws_size,
                              hipStream_t stream) {
    const float* input  = (const float*)d_in[0];
    const float* target = (const float*)d_in[1];
    float* out = (float*)d_out;   // 129 floats

    float* sdtw = (float*)d_ws;                 // 512 floats
    float* wlt  = sdtw + BC_TOT;                // 512 floats

    dtw_fwd_kernel<<<BC_TOT, 192, 0, stream>>>(input, target, sdtw, wlt);
    finalize_kernel<<<1, 64, 0, stream>>>(sdtw, wlt, out);
}